// Round 18
// baseline (642.949 us; speedup 1.0000x reference)
//
#include <hip/hip_runtime.h>
#include <hip/hip_bf16.h>
#include <math.h>

#define K_CODES 8192
#define D_DIM   512
#define N_ROWS  16384
#define DECAYF  0.99f
#define OMDF    0.01f
#define COMMIT  0.25f
#define EPSV    1e-5f

// output offsets (in floats), reference return order:
// z_q_st (8*2048*512), loss (1), indices (8*2048), new_embedding (8192*512),
// ema_cs (8192), ema_es (8192*512)
#define OUT0_OFF 0ull
#define OUT1_OFF 8388608ull
#define OUT2_OFF 8388609ull
#define OUT3_OFF 8404993ull
#define OUT4_OFF 12599297ull
#define OUT5_OFF 12607489ull

#define BM 128
#define BN 256
#define BKC 32
#define NRB (N_ROWS / BM)    // 128 rowblocks
#define NCB (K_CODES / BN)   // 32 colblocks
#define NITER (D_DIM / BKC)  // 16

typedef _Float16 f16x8 __attribute__((ext_vector_type(8)));
typedef _Float16 f16x4 __attribute__((ext_vector_type(4)));
typedef float    f32x4 __attribute__((ext_vector_type(4)));
typedef unsigned short u16;

#define GLOAD16(srcp, dstp) __builtin_amdgcn_global_load_lds( \
    (const __attribute__((address_space(1))) unsigned int*)(const void*)(srcp), \
    (__attribute__((address_space(3))) unsigned int*)(void*)(dstp), 16, 0, 0)

// ---------------- fused prep: pack z/E (hi/lo f16, chunk-packed) + numpy norms ----
// pack layout (16B granules): pack[((pb*16+t)*2+plane)*8192 + (g*256+r)*8 + e]
// holding src[pb*256 + r][t*32 + g*8 .. +7]; bytes identical to r8-r17 pack.
__device__ __forceinline__ void pack_tile(const float* __restrict__ src,
                                          u16* __restrict__ dst, float scale,
                                          int pb, int t, int tid,
                                          u16 (*simg)[1024][8]) {
    const float4* base = (const float4*)(src + ((size_t)pb * 256) * D_DIM + t * 32);
#pragma unroll
    for (int i = 0; i < 8; i++) {
        int f = tid + i * 256;           // 0..2047 float4s of the 256x8 tile
        int r = f >> 3, c = f & 7;
        float4 v = base[(size_t)r * 128 + c];   // row stride = 512 floats
        float s0 = v.x * scale, s1 = v.y * scale, s2 = v.z * scale, s3 = v.w * scale;
        _Float16 h0 = (_Float16)s0, h1 = (_Float16)s1, h2 = (_Float16)s2, h3 = (_Float16)s3;
        f16x4 hv = {h0, h1, h2, h3};
        f16x4 lv = {(_Float16)(s0 - (float)h0), (_Float16)(s1 - (float)h1),
                    (_Float16)(s2 - (float)h2), (_Float16)(s3 - (float)h3)};
        int slot = (c >> 1) * 256 + r;
        int half = (c & 1) * 4;
        *(f16x4*)&simg[0][slot][half] = hv;
        *(f16x4*)&simg[1][slot][half] = lv;
    }
    __syncthreads();
    const u16* flat = &simg[0][0][0];
    u16* gout = dst + ((size_t)pb * 16 + t) * 2 * 8192;
#pragma unroll
    for (int i = 0; i < 8; i++) {
        int g = tid + i * 256;           // granule 0..2047 (plane-major)
        *(f16x8*)(gout + (size_t)g * 8) = *(const f16x8*)(flat + (size_t)g * 8);
    }
}

// numpy pairwise(512) = ((B0+B1)+(B2+B3)); base-128: 8 stride-8 accumulators,
// combined ((r0+r1)+(r2+r3))+((r4+r5)+(r6+r7)). IEEE RN add commutes, so the
// shfl_xor tree reproduces numpy's exact operand pairing. 8 rows / 256-thr block.
__device__ __forceinline__ void norms8(const float* __restrict__ src,
                                       float* __restrict__ dst, int rowbase, int tid) {
    int lane = tid & 63;
    int wave = tid >> 6;
    int half = lane >> 5;
    int l32  = lane & 31;
    int row  = rowbase + wave * 2 + half;
    int j    = l32 & 7;
    int blk  = l32 >> 3;
    const float* p = src + (size_t)row * D_DIM + blk * 128 + j;
    float x0 = p[0];
    float r = __fmul_rn(x0, x0);
#pragma unroll
    for (int i = 1; i < 16; i++) {
        float x = p[i * 8];
        r = __fadd_rn(r, __fmul_rn(x, x));
    }
    float s1 = __fadd_rn(r,  __shfl_xor(r, 1, 64));
    float s2 = __fadd_rn(s1, __shfl_xor(s1, 2, 64));
    float s4 = __fadd_rn(s2, __shfl_xor(s2, 4, 64));
    float t1 = __fadd_rn(s4, __shfl_xor(s4, 8, 64));
    float t2 = __fadd_rn(t1, __shfl_xor(t1, 16, 64));
    if (l32 == 0) dst[row] = t2;
}

__global__ void prep_kernel(const float* __restrict__ z, const float* __restrict__ E,
                            u16* __restrict__ zpack, u16* __restrict__ epack,
                            float* __restrict__ z2, float* __restrict__ e2,
                            int* __restrict__ cnt, float* __restrict__ loss) {
    __shared__ __align__(16) u16 simg[2][1024][8];   // 32 KB (pack branches)
    int bid = blockIdx.x;
    int tid = threadIdx.x;
    if (bid < 1024) {                    // pack z: 64 panels x 16 chunks
        pack_tile(z, zpack, 1.0f, bid >> 4, bid & 15, tid, simg);
    } else if (bid < 1536) {             // pack E: 32 panels x 16 chunks
        int b = bid - 1024;
        pack_tile(E, epack, 4096.0f, b >> 4, b & 15, tid, simg);
    } else if (bid < 3584) {             // z norms: 2048 blocks x 8 rows
        norms8(z, z2, (bid - 1536) * 8, tid);
    } else if (bid < 4608) {             // E norms: 1024 blocks x 8 rows
        norms8(E, e2, (bid - 3584) * 8, tid);
    } else {                             // zero accumulators
#pragma unroll
        for (int i = 0; i < 32; i++) cnt[tid + i * 256] = 0;
        if (tid == 0) loss[0] = 0.f;
    }
}

// ---------------- MFMA distance GEMM + argmin (A in registers, B in LDS) ----------
// dist = fl( fl(z2 - acc*2^-11) + e2 ), acc = 3-product split dot * 4096.
// The LDS unit's ds_read issue rate (~12cyc/ds_read_b128) was the co-bottleneck
// with MFMA. A-fragments are lane-addressable in the packed image, so each wave
// loads its 8 A-frags global->register (coalesced 1KB/wave-instr, L2-hot) and
// LDS carries only B (double-buffered, staged 1 chunk ahead). A-loads issue
// BEFORE stageB so compiler in-order vmcnt waits never drain the younger B DMA.
// Per-acc product order (hh,hl,lh; chunks ascending) unchanged -> identical idx.
__global__ __launch_bounds__(512, 4) void argmin_mfma_kernel(
    const u16* __restrict__ zpack, const u16* __restrict__ epack,
    const float* __restrict__ e2, const float* __restrict__ z2,
    float* __restrict__ pv, int* __restrict__ pi)
{
    __shared__ __align__(16) u16 ldsB[2][2][1024][8];   // [buf][hi/lo][slot][8] 64 KB

    int bid = blockIdx.x;
    int xcd = bid & 7, sub = bid >> 3;       // 4096 = 8 XCDs * 512
    int rb  = sub >> 2;                      // cb-inner: 4 blocks sharing rb run
    int cb  = xcd * 4 + (sub & 3);           //   back-to-back; 4 E-panels/XCD in L2
    int row0 = rb * BM, col0 = cb * BN;
    int pb   = rb >> 1, phalf = rb & 1;      // zpack panels are 256 rows

    int tid = threadIdx.x;
    int l   = tid & 63;
    int w   = tid >> 6;
    int mw  = w >> 2, nw = w & 3;            // wave grid 2(m) x 4(n), 64x64 per wave
    int lg  = l >> 4;                        // k-group 0..3
    int l16 = l & 15;

    f32x4 acc[4][4];
#pragma unroll
    for (int m = 0; m < 4; m++)
#pragma unroll
        for (int n = 0; n < 4; n++)
            acc[m][n] = (f32x4){0.f, 0.f, 0.f, 0.f};

    auto stageB = [&](int buf, int t) {      // 4 gload_lds/thread, double buffer
        const u16* eb = epack + (((size_t)cb * 16 + t) * 2) * 8192;
#pragma unroll
        for (int i = 0; i < 2; i++) {
            int slot = tid + i * 512;
            GLOAD16(eb + (size_t)slot * 8,        &ldsB[buf][0][slot][0]);
            GLOAD16(eb + 8192 + (size_t)slot * 8, &ldsB[buf][1][slot][0]);
        }
    };

    // per-wave A fragment granule index within a zpack plane
    int sA0 = lg * 128 + mw * 64 + l16;      // m=0 slot; +16 per m
    stageB(0, 0);   // prologue: B(0) in flight

    for (int t = 0; t < NITER; t++) {
        int cur = t & 1;
        // B(t) DMA is 1 chunk old -> vmcnt(0) ~free; lgkm: bufs' reads retired
        asm volatile("s_waitcnt vmcnt(0) lgkmcnt(0)" ::: "memory");
        __builtin_amdgcn_s_barrier();
        asm volatile("" ::: "memory");

        // A-frags global->reg (older than stageB -> compiler waits don't drain B)
        f16x8 ah[4], al[4];
        {
            const u16* zb = zpack + (((size_t)pb * 16 + t) * 2) * 8192;
#pragma unroll
            for (int m = 0; m < 4; m++) {
                int s = sA0 + m * 16;
                int gidx = (s >> 7) * 256 + phalf * 128 + (s & 127);
                ah[m] = *(const f16x8*)(zb + (size_t)gidx * 8);
                al[m] = *(const f16x8*)(zb + 8192 + (size_t)gidx * 8);
            }
        }
        if (t + 1 < NITER) stageB(cur ^ 1, t + 1);   // B(t+1): hidden under compute

#pragma unroll
        for (int n = 0; n < 4; n++) {
            int sb = lg * 256 + nw * 64 + n * 16 + l16;
            f16x8 bh = *(const f16x8*)&ldsB[cur][0][sb][0];
            f16x8 bl = *(const f16x8*)&ldsB[cur][1][sb][0];
#pragma unroll
            for (int m = 0; m < 4; m++) {
                acc[m][n] = __builtin_amdgcn_mfma_f32_16x16x32_f16(ah[m], bh, acc[m][n], 0, 0, 0);
                acc[m][n] = __builtin_amdgcn_mfma_f32_16x16x32_f16(ah[m], bl, acc[m][n], 0, 0, 0);
                acc[m][n] = __builtin_amdgcn_mfma_f32_16x16x32_f16(al[m], bh, acc[m][n], 0, 0, 0);
            }
        }
    }

    // ---- epilogue: distances + first-occurrence argmin ----
    const float nscale = -0.00048828125f;   // -2^-11 (undo 4096 scale, apply -2)
    float e2c[4];
#pragma unroll
    for (int n = 0; n < 4; n++) e2c[n] = e2[col0 + nw * 64 + n * 16 + l16];

    __syncthreads();                              // all frag reads done; reuse LDS
    float* redv = (float*)&ldsB[0][0][0][0];      // [128][4] vals (2 KB)
    int*   redi = (int*)&ldsB[1][0][0][0];        // [128][4] idx  (2 KB)

#pragma unroll
    for (int m = 0; m < 4; m++) {
#pragma unroll
        for (int r = 0; r < 4; r++) {
            int rl = mw * 64 + m * 16 + lg * 4 + r;
            float z2v = z2[row0 + rl];
            float bv = 1e30f; int bc = 0x7fffffff;
#pragma unroll
            for (int n = 0; n < 4; n++) {
                int code = col0 + nw * 64 + n * 16 + l16;
                float v = __fadd_rn(__fadd_rn(z2v, __fmul_rn(acc[m][n][r], nscale)), e2c[n]);
                if (v < bv) { bv = v; bc = code; }   // n ascending => code ascending
            }
#pragma unroll
            for (int s = 1; s < 16; s <<= 1) {
                float ov = __shfl_xor(bv, s, 64);
                int   oc = __shfl_xor(bc, s, 64);
                if (ov < bv || (ov == bv && oc < bc)) { bv = ov; bc = oc; }
            }
            if (l16 == r) {
                redv[rl * 4 + nw] = bv;
                redi[rl * 4 + nw] = bc;
            }
        }
    }
    __syncthreads();
    if (tid < BM) {
        float bv = redv[tid * 4]; int bc = redi[tid * 4];
#pragma unroll
        for (int q = 1; q < 4; q++) {
            float v = redv[tid * 4 + q]; int c = redi[tid * 4 + q];
            if (v < bv || (v == bv && c < bc)) { bv = v; bc = c; }
        }
        // transposed layout [row][cb]: combine reads one 128B line per row
        pv[(size_t)(row0 + tid) * NCB + cb] = bv;
        pi[(size_t)(row0 + tid) * NCB + cb] = bc;
    }
}

// ---------------- fused: combine partials + count + gather z_q_st + loss ----------
__global__ void combine_gather_kernel(const float* __restrict__ pv, const int* __restrict__ pi,
                                      const float* __restrict__ z, const float* __restrict__ E,
                                      int* __restrict__ idx_out, float* __restrict__ out2,
                                      int* __restrict__ cnt, float* __restrict__ out0,
                                      float* __restrict__ loss_acc) {
    int row = blockIdx.x;
    int t = threadIdx.x;   // 128
    __shared__ int ksh;
    if (t < 32) {
        float bv = pv[(size_t)row * NCB + t];   // coalesced: one 128B line
        int   bc = pi[(size_t)row * NCB + t];
#pragma unroll
        for (int s = 1; s < 32; s <<= 1) {
            float ov = __shfl_xor(bv, s, 64);
            int   oc = __shfl_xor(bc, s, 64);
            if (ov < bv || (ov == bv && oc < bc)) { bv = ov; bc = oc; }
        }
        if (t == 0) {
            idx_out[row] = bc;
            out2[row] = (float)bc;
            atomicAdd(&cnt[bc], 1);
            ksh = bc;
        }
    }
    __syncthreads();
    int k = ksh;
    int d = t * 4;
    float4 zv = *(const float4*)(z + (size_t)row * D_DIM + d);
    float4 qv = *(const float4*)(E + (size_t)k * D_DIM + d);
    float4 o;
    o.x = __fadd_rn(zv.x, __fsub_rn(qv.x, zv.x));
    o.y = __fadd_rn(zv.y, __fsub_rn(qv.y, zv.y));
    o.z = __fadd_rn(zv.z, __fsub_rn(qv.z, zv.z));
    o.w = __fadd_rn(zv.w, __fsub_rn(qv.w, zv.w));
    *(float4*)(out0 + (size_t)row * D_DIM + d) = o;
    float dx = qv.x - zv.x, dy = qv.y - zv.y, dz = qv.z - zv.z, dw = qv.w - zv.w;
    float s = dx * dx + dy * dy + dz * dz + dw * dw;
#pragma unroll
    for (int off = 32; off; off >>= 1) s += __shfl_down(s, off, 64);
    __shared__ float part[2];
    if ((t & 63) == 0) part[t >> 6] = s;
    __syncthreads();
    if (t == 0) atomicAdd(loss_acc, part[0] + part[1]);
}

// ---------------- block0: exclusive prefix over 8192 counts; block1: cs-sum+loss --
__global__ void prefix_sum_kernel(const int* __restrict__ cnt, int* __restrict__ offs,
                                  const float* __restrict__ cs, float* __restrict__ s_in,
                                  const float* __restrict__ loss_acc, float* __restrict__ out1) {
    if (blockIdx.x == 0) {
        __shared__ int sums[1024];
        int t = threadIdx.x;
        int base = t * 8;
        int loc[8]; int s = 0;
#pragma unroll
        for (int i = 0; i < 8; i++) { loc[i] = s; s += cnt[base + i]; }
        sums[t] = s;
        __syncthreads();
        for (int off = 1; off < 1024; off <<= 1) {
            int v = (t >= off) ? sums[t - off] : 0;
            __syncthreads();
            sums[t] += v;
            __syncthreads();
        }
        int excl = sums[t] - s;
#pragma unroll
        for (int i = 0; i < 8; i++) offs[base + i] = excl + loc[i];
    } else {
        int t = threadIdx.x;
        __shared__ float part[4];
        if (t < 256) {
            float s = 0.f;
            for (int i = t; i < K_CODES; i += 256) s += cs[i];
#pragma unroll
            for (int off = 32; off; off >>= 1) s += __shfl_down(s, off, 64);
            if ((t & 63) == 0) part[t >> 6] = s;
        }
        __syncthreads();
        if (t == 0) {
            s_in[0] = part[0] + part[1] + part[2] + part[3];
            out1[0] = COMMIT * loss_acc[0] / (float)(N_ROWS * D_DIM);
        }
    }
}

// ---------------- scatter rows into per-cluster lists ----------------
__global__ void fill_kernel(const int* __restrict__ idx, int* __restrict__ offs,
                            int* __restrict__ rowlist) {
    int row = blockIdx.x * 256 + threadIdx.x;
    int k = idx[row];
    int pos = atomicAdd(&offs[k], 1);   // offs becomes end-pointer
    rowlist[pos] = row;
}

// ---------------- per-cluster segment sum + EMA + smoothing + new embedding -------
__global__ void cluster_kernel(const float* __restrict__ z, const float* __restrict__ in_cs,
                               const float* __restrict__ in_es, const int* __restrict__ cnt,
                               const int* __restrict__ offs_end, const int* __restrict__ rowlist,
                               const float* __restrict__ s_in,
                               float* __restrict__ out3, float* __restrict__ out4,
                               float* __restrict__ out5) {
    int k = blockIdx.x;
    int t = threadIdx.x;  // 128
    int c = cnt[k];
    int end = offs_end[k];
    int start = end - c;
    int d = t * 4;
    float ax = 0.f, ay = 0.f, az = 0.f, aw = 0.f;
    for (int i = 0; i < c; i++) {
        int row = rowlist[start + i];
        float4 zv = *(const float4*)(z + (size_t)row * D_DIM + d);
        ax += zv.x; ay += zv.y; az += zv.z; aw += zv.w;
    }
    float ema_cs = DECAYF * in_cs[k] + OMDF * (float)c;
    float n = DECAYF * s_in[0] + OMDF * (float)N_ROWS;
    float smoothed = (ema_cs + EPSV) / (n + (float)K_CODES * EPSV) * n;
    float4 esv = *(const float4*)(in_es + (size_t)k * D_DIM + d);
    float4 ema;
    ema.x = DECAYF * esv.x + OMDF * ax;
    ema.y = DECAYF * esv.y + OMDF * ay;
    ema.z = DECAYF * esv.z + OMDF * az;
    ema.w = DECAYF * esv.w + OMDF * aw;
    *(float4*)(out5 + (size_t)k * D_DIM + d) = ema;
    float4 emb;
    emb.x = ema.x / smoothed;
    emb.y = ema.y / smoothed;
    emb.z = ema.z / smoothed;
    emb.w = ema.w / smoothed;
    *(float4*)(out3 + (size_t)k * D_DIM + d) = emb;
    if (t == 0) out4[k] = ema_cs;
}

extern "C" void kernel_launch(void* const* d_in, const int* in_sizes, int n_in,
                              void* d_out, int out_size, void* d_ws, size_t ws_size,
                              hipStream_t stream) {
    const float* z     = (const float*)d_in[0];
    const float* E     = (const float*)d_in[1];
    const float* in_cs = (const float*)d_in[2];
    const float* in_es = (const float*)d_in[3];

    float* out  = (float*)d_out;
    float* out0 = out + OUT0_OFF;
    float* out1 = out + OUT1_OFF;
    float* out2 = out + OUT2_OFF;
    float* out3 = out + OUT3_OFF;
    float* out4 = out + OUT4_OFF;
    float* out5 = out + OUT5_OFF;

    // chunk-packed hi/lo fp16 planes stashed in output regions (overwritten later):
    u16* zpack = (u16*)out0;                                 // 32 MB = out0 exactly
    u16* epack = (u16*)(out + OUT3_OFF + 3);                 // 16 MB; spills 3 floats into out4 (rewritten by cluster)
    // argmin partials scratch in out5 region (fully rewritten by cluster_kernel):
    float* pv = out5;                                        // [row][cb] 2 MB
    int*   pi = (int*)(out5 + (size_t)NCB * N_ROWS);         // 2 MB

    char* ws = (char*)d_ws;
    float* e2      = (float*)(ws);                           // 32 KB
    float* z2      = (float*)(ws + 32 * 1024);               // 64 KB
    int*   idxb    = (int*)  (ws + 96 * 1024);               // 64 KB
    int*   cnt     = (int*)  (ws + 160 * 1024);              // 32 KB
    int*   offs    = (int*)  (ws + 192 * 1024);              // 32 KB
    int*   rowlist = (int*)  (ws + 224 * 1024);              // 64 KB
    float* loss    = (float*)(ws + 288 * 1024);              // 4 B
    float* s_in    = loss + 1;                               // 4 B

    prep_kernel<<<4609, 256, 0, stream>>>(z, E, zpack, epack, z2, e2, cnt, loss);
    argmin_mfma_kernel<<<NRB * NCB, 512, 0, stream>>>(zpack, epack, e2, z2, pv, pi);
    combine_gather_kernel<<<N_ROWS, 128, 0, stream>>>(pv, pi, z, E, idxb, out2, cnt,
                                                      out0, loss);
    prefix_sum_kernel<<<2, 1024, 0, stream>>>(cnt, offs, in_cs, s_in, loss, out1);
    fill_kernel<<<N_ROWS / 256, 256, 0, stream>>>(idxb, offs, rowlist);
    cluster_kernel<<<K_CODES, 128, 0, stream>>>(z, in_cs, in_es, cnt, offs, rowlist,
                                                s_in, out3, out4, out5);
}

// Round 19
// 454.027 us; speedup vs baseline: 1.4161x; 1.4161x over previous
//
#include <hip/hip_runtime.h>
#include <hip/hip_bf16.h>
#include <math.h>

#define K_CODES 8192
#define D_DIM   512
#define N_ROWS  16384
#define DECAYF  0.99f
#define OMDF    0.01f
#define COMMIT  0.25f
#define EPSV    1e-5f

// output offsets (in floats), reference return order:
// z_q_st (8*2048*512), loss (1), indices (8*2048), new_embedding (8192*512),
// ema_cs (8192), ema_es (8192*512)
#define OUT0_OFF 0ull
#define OUT1_OFF 8388608ull
#define OUT2_OFF 8388609ull
#define OUT3_OFF 8404993ull
#define OUT4_OFF 12599297ull
#define OUT5_OFF 12607489ull

#define BM 128
#define BN 256
#define BKC 32
#define NRB (N_ROWS / BM)    // 128 rowblocks
#define NCB (K_CODES / BN)   // 32 colblocks
#define NITER (D_DIM / BKC)  // 16
#define NLBUCK 512

typedef _Float16 f16x8 __attribute__((ext_vector_type(8)));
typedef _Float16 f16x4 __attribute__((ext_vector_type(4)));
typedef float    f32x4 __attribute__((ext_vector_type(4)));
typedef unsigned short u16;

#define GLOAD16(srcp, dstp) __builtin_amdgcn_global_load_lds( \
    (const __attribute__((address_space(1))) unsigned int*)(const void*)(srcp), \
    (__attribute__((address_space(3))) unsigned int*)(void*)(dstp), 16, 0, 0)

// ---------------- fused prep: pack z/E (hi/lo f16, chunk-packed) + numpy norms ----
// pack layout (16B granules): pack[((pb*16+t)*2+plane)*8192 + (g*256+r)*8 + e]
// holding src[pb*256 + r][t*32 + g*8 .. +7]; bytes identical to r8-r18 pack.
__device__ __forceinline__ void pack_tile(const float* __restrict__ src,
                                          u16* __restrict__ dst, float scale,
                                          int pb, int t, int tid,
                                          u16 (*simg)[1024][8]) {
    const float4* base = (const float4*)(src + ((size_t)pb * 256) * D_DIM + t * 32);
#pragma unroll
    for (int i = 0; i < 8; i++) {
        int f = tid + i * 256;           // 0..2047 float4s of the 256x8 tile
        int r = f >> 3, c = f & 7;
        float4 v = base[(size_t)r * 128 + c];   // row stride = 512 floats
        float s0 = v.x * scale, s1 = v.y * scale, s2 = v.z * scale, s3 = v.w * scale;
        _Float16 h0 = (_Float16)s0, h1 = (_Float16)s1, h2 = (_Float16)s2, h3 = (_Float16)s3;
        f16x4 hv = {h0, h1, h2, h3};
        f16x4 lv = {(_Float16)(s0 - (float)h0), (_Float16)(s1 - (float)h1),
                    (_Float16)(s2 - (float)h2), (_Float16)(s3 - (float)h3)};
        int slot = (c >> 1) * 256 + r;
        int half = (c & 1) * 4;
        *(f16x4*)&simg[0][slot][half] = hv;
        *(f16x4*)&simg[1][slot][half] = lv;
    }
    __syncthreads();
    const u16* flat = &simg[0][0][0];
    u16* gout = dst + ((size_t)pb * 16 + t) * 2 * 8192;
#pragma unroll
    for (int i = 0; i < 8; i++) {
        int g = tid + i * 256;           // granule 0..2047 (plane-major)
        *(f16x8*)(gout + (size_t)g * 8) = *(const f16x8*)(flat + (size_t)g * 8);
    }
}

// numpy pairwise(512) = ((B0+B1)+(B2+B3)); base-128: 8 stride-8 accumulators,
// combined ((r0+r1)+(r2+r3))+((r4+r5)+(r6+r7)). IEEE RN add commutes, so the
// shfl_xor tree reproduces numpy's exact operand pairing. 8 rows / 256-thr block.
__device__ __forceinline__ void norms8(const float* __restrict__ src,
                                       float* __restrict__ dst, int rowbase, int tid) {
    int lane = tid & 63;
    int wave = tid >> 6;
    int half = lane >> 5;
    int l32  = lane & 31;
    int row  = rowbase + wave * 2 + half;
    int j    = l32 & 7;
    int blk  = l32 >> 3;
    const float* p = src + (size_t)row * D_DIM + blk * 128 + j;
    float x0 = p[0];
    float r = __fmul_rn(x0, x0);
#pragma unroll
    for (int i = 1; i < 16; i++) {
        float x = p[i * 8];
        r = __fadd_rn(r, __fmul_rn(x, x));
    }
    float s1 = __fadd_rn(r,  __shfl_xor(r, 1, 64));
    float s2 = __fadd_rn(s1, __shfl_xor(s1, 2, 64));
    float s4 = __fadd_rn(s2, __shfl_xor(s2, 4, 64));
    float t1 = __fadd_rn(s4, __shfl_xor(s4, 8, 64));
    float t2 = __fadd_rn(t1, __shfl_xor(t1, 16, 64));
    if (l32 == 0) dst[row] = t2;
}

__global__ void prep_kernel(const float* __restrict__ z, const float* __restrict__ E,
                            u16* __restrict__ zpack, u16* __restrict__ epack,
                            float* __restrict__ z2, float* __restrict__ e2,
                            int* __restrict__ cnt, float* __restrict__ lossbuf) {
    __shared__ __align__(16) u16 simg[2][1024][8];   // 32 KB (pack branches)
    int bid = blockIdx.x;
    int tid = threadIdx.x;
    if (bid < 1024) {                    // pack z: 64 panels x 16 chunks
        pack_tile(z, zpack, 1.0f, bid >> 4, bid & 15, tid, simg);
    } else if (bid < 1536) {             // pack E: 32 panels x 16 chunks
        int b = bid - 1024;
        pack_tile(E, epack, 4096.0f, b >> 4, b & 15, tid, simg);
    } else if (bid < 3584) {             // z norms: 2048 blocks x 8 rows
        norms8(z, z2, (bid - 1536) * 8, tid);
    } else if (bid < 4608) {             // E norms: 1024 blocks x 8 rows
        norms8(E, e2, (bid - 3584) * 8, tid);
    } else {                             // zero accumulators
#pragma unroll
        for (int i = 0; i < 32; i++) cnt[tid + i * 256] = 0;
        lossbuf[tid] = 0.f;
        lossbuf[tid + 256] = 0.f;
    }
}

// ---------------- MFMA distance GEMM + argmin (r17 trunk, frozen) -----------------
// dist = fl( fl(z2 - acc*2^-11) + e2 ), acc = 3-product split dot * 4096.
// 128x256, 2 blocks/CU; B double-buffered, staged one chunk ahead; counted
// s_waitcnt vmcnt(4) keeps B(t+1) in flight across compute. MFMA order
// identical to r9..r17 -> identical indices. Partials written [row][cb].
__global__ __launch_bounds__(512, 4) void argmin_mfma_kernel(
    const u16* __restrict__ zpack, const u16* __restrict__ epack,
    const float* __restrict__ e2, const float* __restrict__ z2,
    float* __restrict__ pv, int* __restrict__ pi)
{
    __shared__ __align__(16) u16 ldsA[2][512][8];       // [hi/lo][g*128+row][8] 16 KB
    __shared__ __align__(16) u16 ldsB[2][2][1024][8];   // [buf][hi/lo][slot][8] 64 KB

    int bid = blockIdx.x;
    int xcd = bid & 7, sub = bid >> 3;       // 4096 = 8 XCDs * 512
    int rb  = sub >> 2;                      // cb-inner: 4 blocks sharing rb run
    int cb  = xcd * 4 + (sub & 3);           //   back-to-back; 4 E-panels/XCD in L2
    int row0 = rb * BM, col0 = cb * BN;
    int pb   = rb >> 1, phalf = rb & 1;      // zpack panels are 256 rows

    int tid = threadIdx.x;
    int l   = tid & 63;
    int w   = tid >> 6;
    int mw  = w >> 2, nw = w & 3;            // wave grid 2(m) x 4(n), 64x64 per wave
    int lg  = l >> 4;                        // k-group 0..3
    int l16 = l & 15;

    f32x4 acc[4][4];
#pragma unroll
    for (int m = 0; m < 4; m++)
#pragma unroll
        for (int n = 0; n < 4; n++)
            acc[m][n] = (f32x4){0.f, 0.f, 0.f, 0.f};

    auto stageA = [&](int t) {               // 2 gload/thread, single buffer
        const u16* zb = zpack + (((size_t)pb * 16 + t) * 2) * 8192;
#pragma unroll
        for (int i = 0; i < 2; i++) {
            int idx = tid + i * 512;     // 0..1023
            int p = idx >> 9, rem = idx & 511;
            int g = rem >> 7, r = rem & 127;
            GLOAD16(zb + ((size_t)p * 1024 + g * 256 + phalf * 128 + r) * 8,
                    &ldsA[p][g * 128 + r][0]);
        }
    };
    auto stageB = [&](int buf, int t) {      // 4 gload/thread, double buffer
        const u16* eb = epack + (((size_t)cb * 16 + t) * 2) * 8192;
#pragma unroll
        for (int i = 0; i < 2; i++) {
            int slot = tid + i * 512;
            GLOAD16(eb + (size_t)slot * 8,        &ldsB[buf][0][slot][0]);
            GLOAD16(eb + 8192 + (size_t)slot * 8, &ldsB[buf][1][slot][0]);
        }
    };

    stageB(0, 0);   // prologue: B(0) in flight

    for (int t = 0; t < NITER; t++) {
        int cur = t & 1;
        // barrier 1: all waves' ds_reads of A(t-1) retired -> safe to overwrite A
        asm volatile("s_waitcnt lgkmcnt(0)" ::: "memory");
        __builtin_amdgcn_s_barrier();
        asm volatile("" ::: "memory");

        stageA(t);                                   // A(t): 2 loads (exposed, small)
        if (t + 1 < NITER) stageB(cur ^ 1, t + 1);   // B(t+1): 4 loads (hidden)

        // retire [B(t):4, A(t):2]; keep B(t+1):4 in flight across compute
        if (t + 1 < NITER) { asm volatile("s_waitcnt vmcnt(4)" ::: "memory"); }
        else               { asm volatile("s_waitcnt vmcnt(0)" ::: "memory"); }
        __builtin_amdgcn_s_barrier();
        asm volatile("" ::: "memory");

        f16x8 bh[4], bl[4];
#pragma unroll
        for (int n = 0; n < 4; n++) {
            int s = lg * 256 + nw * 64 + n * 16 + l16;
            bh[n] = *(const f16x8*)&ldsB[cur][0][s][0];
            bl[n] = *(const f16x8*)&ldsB[cur][1][s][0];
        }
#pragma unroll
        for (int m = 0; m < 4; m++) {
            int s = lg * 128 + mw * 64 + m * 16 + l16;
            f16x8 ah = *(const f16x8*)&ldsA[0][s][0];
            f16x8 al = *(const f16x8*)&ldsA[1][s][0];
#pragma unroll
            for (int n = 0; n < 4; n++)
                acc[m][n] = __builtin_amdgcn_mfma_f32_16x16x32_f16(ah, bh[n], acc[m][n], 0, 0, 0);
#pragma unroll
            for (int n = 0; n < 4; n++)
                acc[m][n] = __builtin_amdgcn_mfma_f32_16x16x32_f16(ah, bl[n], acc[m][n], 0, 0, 0);
#pragma unroll
            for (int n = 0; n < 4; n++)
                acc[m][n] = __builtin_amdgcn_mfma_f32_16x16x32_f16(al, bh[n], acc[m][n], 0, 0, 0);
        }
    }

    // ---- epilogue: distances + first-occurrence argmin ----
    const float nscale = -0.00048828125f;   // -2^-11 (undo 4096 scale, apply -2)
    float e2c[4];
#pragma unroll
    for (int n = 0; n < 4; n++) e2c[n] = e2[col0 + nw * 64 + n * 16 + l16];

    __syncthreads();                              // all frag reads done; reuse LDS
    float* redv = (float*)&ldsA[0][0][0];         // [128][4] vals (2 KB)
    int*   redi = (int*)&ldsB[0][0][0][0];        // [128][4] idx  (2 KB)

#pragma unroll
    for (int m = 0; m < 4; m++) {
#pragma unroll
        for (int r = 0; r < 4; r++) {
            int rl = mw * 64 + m * 16 + lg * 4 + r;
            float z2v = z2[row0 + rl];
            float bv = 1e30f; int bc = 0x7fffffff;
#pragma unroll
            for (int n = 0; n < 4; n++) {
                int code = col0 + nw * 64 + n * 16 + l16;
                float v = __fadd_rn(__fadd_rn(z2v, __fmul_rn(acc[m][n][r], nscale)), e2c[n]);
                if (v < bv) { bv = v; bc = code; }   // n ascending => code ascending
            }
#pragma unroll
            for (int s = 1; s < 16; s <<= 1) {
                float ov = __shfl_xor(bv, s, 64);
                int   oc = __shfl_xor(bc, s, 64);
                if (ov < bv || (ov == bv && oc < bc)) { bv = ov; bc = oc; }
            }
            if (l16 == r) {
                redv[rl * 4 + nw] = bv;
                redi[rl * 4 + nw] = bc;
            }
        }
    }
    __syncthreads();
    if (tid < BM) {
        float bv = redv[tid * 4]; int bc = redi[tid * 4];
#pragma unroll
        for (int q = 1; q < 4; q++) {
            float v = redv[tid * 4 + q]; int c = redi[tid * 4 + q];
            if (v < bv || (v == bv && c < bc)) { bv = v; bc = c; }
        }
        // transposed layout [row][cb]: combine reads one 128B line per row
        pv[(size_t)(row0 + tid) * NCB + cb] = bv;
        pi[(size_t)(row0 + tid) * NCB + cb] = bc;
    }
}

// ---------------- fused: combine partials + count + gather z_q_st + loss ----------
__global__ void combine_gather_kernel(const float* __restrict__ pv, const int* __restrict__ pi,
                                      const float* __restrict__ z, const float* __restrict__ E,
                                      int* __restrict__ idx_out, float* __restrict__ out2,
                                      int* __restrict__ cnt, float* __restrict__ out0,
                                      float* __restrict__ lossbuf) {
    int row = blockIdx.x;
    int t = threadIdx.x;   // 128
    __shared__ int ksh;
    if (t < 32) {
        float bv = pv[(size_t)row * NCB + t];   // coalesced: one 128B line
        int   bc = pi[(size_t)row * NCB + t];
#pragma unroll
        for (int s = 1; s < 32; s <<= 1) {
            float ov = __shfl_xor(bv, s, 64);
            int   oc = __shfl_xor(bc, s, 64);
            if (ov < bv || (ov == bv && oc < bc)) { bv = ov; bc = oc; }
        }
        if (t == 0) {
            idx_out[row] = bc;
            out2[row] = (float)bc;
            atomicAdd(&cnt[bc], 1);
            ksh = bc;
        }
    }
    __syncthreads();
    int k = ksh;
    int d = t * 4;
    float4 zv = *(const float4*)(z + (size_t)row * D_DIM + d);
    float4 qv = *(const float4*)(E + (size_t)k * D_DIM + d);
    float4 o;
    o.x = __fadd_rn(zv.x, __fsub_rn(qv.x, zv.x));
    o.y = __fadd_rn(zv.y, __fsub_rn(qv.y, zv.y));
    o.z = __fadd_rn(zv.z, __fsub_rn(qv.z, zv.z));
    o.w = __fadd_rn(zv.w, __fsub_rn(qv.w, zv.w));
    *(float4*)(out0 + (size_t)row * D_DIM + d) = o;
    float dx = qv.x - zv.x, dy = qv.y - zv.y, dz = qv.z - zv.z, dw = qv.w - zv.w;
    float s = dx * dx + dy * dy + dz * dz + dw * dw;
#pragma unroll
    for (int off = 32; off; off >>= 1) s += __shfl_down(s, off, 64);
    __shared__ float part[2];
    if ((t & 63) == 0) part[t >> 6] = s;
    __syncthreads();
    if (t == 0) atomicAdd(&lossbuf[row & (NLBUCK - 1)], part[0] + part[1]);
}

// ---------------- single-block mid: prefix + fill + cs-sum + loss finalize --------
__global__ void mid_kernel(const int* __restrict__ cnt, int* __restrict__ offs,
                           const int* __restrict__ idx, int* __restrict__ rowlist,
                           const float* __restrict__ cs, float* __restrict__ s_in,
                           const float* __restrict__ lossbuf, float* __restrict__ out1) {
    __shared__ int loc_offs[K_CODES];   // 32 KB
    __shared__ int sums[1024];
    __shared__ float fpart[16];
    int t = threadIdx.x;                // 1024
    int base = t * 8;
    int loc[8]; int s = 0;
#pragma unroll
    for (int i = 0; i < 8; i++) { loc[i] = s; s += cnt[base + i]; }
    sums[t] = s;
    __syncthreads();
    for (int off = 1; off < 1024; off <<= 1) {
        int v = (t >= off) ? sums[t - off] : 0;
        __syncthreads();
        sums[t] += v;
        __syncthreads();
    }
    int excl = sums[t] - s;
#pragma unroll
    for (int i = 0; i < 8; i++) loc_offs[base + i] = excl + loc[i];
    __syncthreads();
    // fill rowlist via LDS atomics (loc_offs become end-pointers)
#pragma unroll
    for (int i = 0; i < 16; i++) {
        int row = i * 1024 + t;
        int k = idx[row];
        int pos = atomicAdd(&loc_offs[k], 1);
        rowlist[pos] = row;
    }
    __syncthreads();
#pragma unroll
    for (int i = 0; i < 8; i++) offs[base + i] = loc_offs[base + i];   // end ptrs
    // cs sum (exact order irrelevant: only feeds smoothing, 2% tolerance)
    float fs = 0.f;
    for (int i = t; i < K_CODES; i += 1024) fs += cs[i];
#pragma unroll
    for (int off = 32; off; off >>= 1) fs += __shfl_down(fs, off, 64);
    if ((t & 63) == 0) fpart[t >> 6] = fs;
    __syncthreads();
    if (t == 0) {
        float tot = 0.f;
#pragma unroll
        for (int i = 0; i < 16; i++) tot += fpart[i];
        s_in[0] = tot;
    }
    __syncthreads();
    // loss: sum 512 buckets
    float ls = (t < NLBUCK) ? lossbuf[t] : 0.f;
#pragma unroll
    for (int off = 32; off; off >>= 1) ls += __shfl_down(ls, off, 64);
    if ((t & 63) == 0) fpart[t >> 6] = ls;
    __syncthreads();
    if (t == 0) {
        float tot = 0.f;
#pragma unroll
        for (int i = 0; i < 16; i++) tot += fpart[i];
        out1[0] = COMMIT * tot / (float)(N_ROWS * D_DIM);
    }
}

// ---------------- per-cluster segment sum + EMA + smoothing + new embedding -------
__global__ void cluster_kernel(const float* __restrict__ z, const float* __restrict__ in_cs,
                               const float* __restrict__ in_es, const int* __restrict__ cnt,
                               const int* __restrict__ offs_end, const int* __restrict__ rowlist,
                               const float* __restrict__ s_in,
                               float* __restrict__ out3, float* __restrict__ out4,
                               float* __restrict__ out5) {
    int k = blockIdx.x;
    int t = threadIdx.x;  // 128
    int c = cnt[k];
    int end = offs_end[k];
    int start = end - c;
    int d = t * 4;
    float ax = 0.f, ay = 0.f, az = 0.f, aw = 0.f;
    for (int i = 0; i < c; i++) {
        int row = rowlist[start + i];
        float4 zv = *(const float4*)(z + (size_t)row * D_DIM + d);
        ax += zv.x; ay += zv.y; az += zv.z; aw += zv.w;
    }
    float ema_cs = DECAYF * in_cs[k] + OMDF * (float)c;
    float n = DECAYF * s_in[0] + OMDF * (float)N_ROWS;
    float smoothed = (ema_cs + EPSV) / (n + (float)K_CODES * EPSV) * n;
    float4 esv = *(const float4*)(in_es + (size_t)k * D_DIM + d);
    float4 ema;
    ema.x = DECAYF * esv.x + OMDF * ax;
    ema.y = DECAYF * esv.y + OMDF * ay;
    ema.z = DECAYF * esv.z + OMDF * az;
    ema.w = DECAYF * esv.w + OMDF * aw;
    *(float4*)(out5 + (size_t)k * D_DIM + d) = ema;
    float4 emb;
    emb.x = ema.x / smoothed;
    emb.y = ema.y / smoothed;
    emb.z = ema.z / smoothed;
    emb.w = ema.w / smoothed;
    *(float4*)(out3 + (size_t)k * D_DIM + d) = emb;
    if (t == 0) out4[k] = ema_cs;
}

extern "C" void kernel_launch(void* const* d_in, const int* in_sizes, int n_in,
                              void* d_out, int out_size, void* d_ws, size_t ws_size,
                              hipStream_t stream) {
    const float* z     = (const float*)d_in[0];
    const float* E     = (const float*)d_in[1];
    const float* in_cs = (const float*)d_in[2];
    const float* in_es = (const float*)d_in[3];

    float* out  = (float*)d_out;
    float* out0 = out + OUT0_OFF;
    float* out1 = out + OUT1_OFF;
    float* out2 = out + OUT2_OFF;
    float* out3 = out + OUT3_OFF;
    float* out4 = out + OUT4_OFF;
    float* out5 = out + OUT5_OFF;

    // chunk-packed hi/lo fp16 planes stashed in output regions (overwritten later):
    u16* zpack = (u16*)out0;                                 // 32 MB = out0 exactly
    u16* epack = (u16*)(out + OUT3_OFF + 3);                 // 16 MB; spills 3 floats into out4 (rewritten by cluster)
    // argmin partials scratch in out5 region (fully rewritten by cluster_kernel):
    float* pv = out5;                                        // [row][cb] 2 MB
    int*   pi = (int*)(out5 + (size_t)NCB * N_ROWS);         // 2 MB

    char* ws = (char*)d_ws;
    float* e2      = (float*)(ws);                           // 32 KB
    float* z2      = (float*)(ws + 32 * 1024);               // 64 KB
    int*   idxb    = (int*)  (ws + 96 * 1024);               // 64 KB
    int*   cnt     = (int*)  (ws + 160 * 1024);              // 32 KB
    int*   offs    = (int*)  (ws + 192 * 1024);              // 32 KB
    int*   rowlist = (int*)  (ws + 224 * 1024);              // 64 KB
    float* lossbuf = (float*)(ws + 288 * 1024);              // 2 KB
    float* s_in    = (float*)(ws + 292 * 1024);              // 4 B

    prep_kernel<<<4609, 256, 0, stream>>>(z, E, zpack, epack, z2, e2, cnt, lossbuf);
    argmin_mfma_kernel<<<NRB * NCB, 512, 0, stream>>>(zpack, epack, e2, z2, pv, pi);
    combine_gather_kernel<<<N_ROWS, 128, 0, stream>>>(pv, pi, z, E, idxb, out2, cnt,
                                                      out0, lossbuf);
    mid_kernel<<<1, 1024, 0, stream>>>(cnt, offs, idxb, rowlist, in_cs, s_in,
                                       lossbuf, out1);
    cluster_kernel<<<K_CODES, 128, 0, stream>>>(z, in_cs, in_es, cnt, offs, rowlist,
                                                s_in, out3, out4, out5);
}